// Round 16
// baseline (81.196 us; speedup 1.0000x reference)
//
#include <hip/hip_runtime.h>

// MTRNN single step, SINGLE-LAUNCH megakernel. Live computation (DCE'd):
//   io_new = tanh([x|io|cf] @ (0.5*[Wi2io | Wio2io+I | Wcf2io])^T + bsum)
//   y      = tanh(io_new @ Wio2o^T + bio2o)
// Grid 256 (== #CUs, 1 block/CU by capacity: 144KB LDS, 512 thr) x 3 phases
// separated by atomic grid barriers (+agent fences for cross-XCD visibility):
//   phase 0: weight convert -> wcat/w2s/bsum (chunk-XOR swizzled)
//   phase 1: gemm1 = r8's proven 3-buffer counted-vmcnt pipeline (BM=BN=128)
//   phase 2: gemm2, BM=32 BN=128, double-K staging (uniform 5 loads/wave)
// This removes the ~9us of inter-kernel launch/drain gaps of the 3-kernel
// chain (r11's budget: prep 12 + gemm1 9 + gemm2 3 + OH 9 = 33).

typedef float f32x4 __attribute__((ext_vector_type(4)));
typedef __bf16 bf16x4 __attribute__((ext_vector_type(4)));
typedef __bf16 bf16x8 __attribute__((ext_vector_type(8)));
typedef unsigned short u16x4 __attribute__((ext_vector_type(4)));

__device__ __forceinline__ unsigned short f2bf(float f) {
    unsigned u = __builtin_bit_cast(unsigned, f);
    u += 0x7FFFu + ((u >> 16) & 1u);
    return (unsigned short)(u >> 16);
}

__device__ __forceinline__ float tanh_fast(float x) {
    float e = __expf(2.0f * x);
    return 1.0f - 2.0f * __builtin_amdgcn_rcpf(e + 1.0f);
}

// async global->LDS, 16B per lane. LDS dest is wave-uniform base + lane*16.
__device__ __forceinline__ void gload16(const void* g, void* l) {
    __builtin_amdgcn_global_load_lds(
        (const __attribute__((address_space(1))) void*)g,
        (__attribute__((address_space(3))) void*)l, 16, 0, 0);
}

// counted wait + barrier: keep newer stages' loads in flight across it.
#define WAITB(N) asm volatile("s_waitcnt vmcnt(" #N ")\n\ts_barrier" ::: "memory")
// plain barrier (guards LDS overwrite after all waves finished reading).
#define BARL()   asm volatile("s_waitcnt lgkmcnt(0)\n\ts_barrier" ::: "memory")

// Grid-wide barrier: generation counter in global memory. bar[0]=arrive,
// bar[1]=generation (zeroed by hipMemsetAsync each launch).
// __threadfence() = agent-scope fence -> L2 writeback/invalidate on gfx950,
// giving cross-XCD visibility of pre-barrier stores.
__device__ __forceinline__ void grid_barrier(unsigned* bar) {
    __syncthreads();
    if (threadIdx.x == 0) {
        __threadfence();                                  // release my writes
        unsigned gen = atomicAdd(&bar[1], 0u);            // read generation
        __threadfence();                                  // order gen-read < arrive
        unsigned a = atomicAdd(&bar[0], 1u);
        if (a == 255u) {
            atomicExch(&bar[0], 0u);
            __threadfence();
            atomicAdd(&bar[1], 1u);                       // release all
        } else {
            while (atomicAdd(&bar[1], 0u) == gen)
                __builtin_amdgcn_s_sleep(16);
        }
        __threadfence();                                  // acquire
    }
    __syncthreads();
}

// ---------------------------------------------------------------------------
__global__ __launch_bounds__(512, 2) void k_all(
    const float* __restrict__ x, const float* __restrict__ io,
    const float* __restrict__ cf,
    const float* __restrict__ Wi2io, const float* __restrict__ Wio2io,
    const float* __restrict__ Wcf2io, const float* __restrict__ Wio2o,
    const float* __restrict__ b1, const float* __restrict__ b2,
    const float* __restrict__ b3, const float* __restrict__ b4,
    unsigned short* __restrict__ wcat, unsigned short* __restrict__ w2s,
    float* __restrict__ bsum, unsigned short* __restrict__ ionew,
    unsigned* __restrict__ bar, float* __restrict__ out)
{
    __shared__ __align__(16) char lds[147456];

    const int tid = threadIdx.x, b = blockIdx.x;
    const int lane = tid & 63, wid = tid >> 6;
    const int li = lane & 15, lh = lane >> 4;

    // ======================= phase 0: weight convert ========================
    // wcat[512][1152] = 0.5*[Wi2io | Wio2io+I | Wcf2io], chunk-XOR swizzled:
    // (n,k) -> n*L + (k&~63) + ((((k>>3)&7)^(n&7))<<3) + (k&7). w2s likewise.
    #pragma unroll
    for (int it = 0; it < 2; ++it) {
        int idx = it * 131072 + b * 512 + tid;
        if (idx < 147456) {              // 512*1152/4 quads
            int n = idx / 288;
            int k = (idx - n * 288) * 4;
            const float* s;
            if (k < 128)      s = Wi2io  + n * 128 + k;
            else if (k < 640) s = Wio2io + n * 512 + (k - 128);
            else              s = Wcf2io + n * 512 + (k - 640);
            f32x4 v = *(const f32x4*)s;
            u16x4 h;
            #pragma unroll
            for (int t = 0; t < 4; ++t) {
                float f = 0.5f * v[t];
                int kk = k + t;
                if (kk >= 128 && kk < 640 && (kk - 128) == n) f += 0.5f; // +0.5I
                h[t] = f2bf(f);
            }
            int ad = n * 1152 + (k & ~63) +
                     ((((k >> 3) & 7) ^ (n & 7)) << 3) + (k & 7);
            *(u16x4*)(wcat + ad) = h;
        } else if (idx < 163840) {       // w2: 128*512/4 quads
            int q = idx - 147456;
            int n = q >> 7;
            int k = (q & 127) * 4;
            f32x4 v = *(const f32x4*)(Wio2o + n * 512 + k);
            u16x4 h; h[0]=f2bf(v[0]); h[1]=f2bf(v[1]);
            h[2]=f2bf(v[2]); h[3]=f2bf(v[3]);
            int ad = n * 512 + (k & ~63) +
                     ((((k >> 3) & 7) ^ (n & 7)) << 3) + (k & 7);
            *(u16x4*)(w2s + ad) = h;
        } else if (idx < 164352) {
            int n = idx - 163840;
            bsum[n] = 0.5f * (b1[n] + b2[n] + b3[n]);
        }
    }

    grid_barrier(bar);

    // ==================== phase 1: gemm1 (r8 verbatim) ======================
    // BM=128 BN=128 BK=64, 8 waves (4m x 2n, wave 32x64). 3 LDS buffers of
    // 48KB (A f32 32KB @0, B bf16 16KB @32768), counted WAITB(6).
    {
        const int xcd = b & 7, idx1 = b >> 3;            // idx1 0..31
        const int m0 = ((xcd << 3) | (idx1 & 7)) << 7;   // panel*128
        const int n0 = (idx1 >> 3) << 7;                 // colb*128
        const int wm = (wid >> 1) << 5;       // 0/32/64/96
        const int wn = (wid & 1) << 6;        // 0/64

        int a_off_x[4], a_off_s[4], b_off[2];
        #pragma unroll
        for (int j = 0; j < 4; ++j) {
            int r = (wid << 4) + (j << 2) + (lane >> 4);     // A row 0..127
            int cs = (lane & 15) ^ (r & 15);                 // swizzled chunk
            a_off_x[j] = (m0 + r) * 128 + cs * 4;
            a_off_s[j] = (m0 + r) * 512 + cs * 4;
        }
        #pragma unroll
        for (int j = 0; j < 2; ++j) {
            int rb = ((wid << 1) + j) * 8 + (lane >> 3);     // B row 0..127
            b_off[j] = (n0 + rb) * 1152 + ((lane & 7) << 3); // pre-swizzled
        }
        const int adstA = wid << 12;   // + j<<10
        const int adstB = wid << 11;   // + j<<10

        f32x4 zz = {0.f, 0.f, 0.f, 0.f};
        f32x4 acc[2][4];
        #pragma unroll
        for (int i = 0; i < 2; ++i)
            #pragma unroll
            for (int j = 0; j < 4; ++j) acc[i][j] = zz;

#define STAGE1(KT, BUF) do {                                                   \
        int K_ = (KT);                                                         \
        char* A_ = (BUF); char* B_ = (BUF) + 32768;                            \
        if (K_ < 2) {                                                          \
            const float* sp = x + (K_ << 6);                                   \
            _Pragma("unroll")                                                  \
            for (int j = 0; j < 4; ++j)                                        \
                gload16(sp + a_off_x[j], A_ + adstA + (j << 10));              \
        } else if (K_ < 10) {                                                  \
            const float* sp = io + ((K_ - 2) << 6);                            \
            _Pragma("unroll")                                                  \
            for (int j = 0; j < 4; ++j)                                        \
                gload16(sp + a_off_s[j], A_ + adstA + (j << 10));              \
        } else {                                                               \
            const float* sp = cf + ((K_ - 10) << 6);                           \
            _Pragma("unroll")                                                  \
            for (int j = 0; j < 4; ++j)                                        \
                gload16(sp + a_off_s[j], A_ + adstA + (j << 10));              \
        }                                                                      \
        const unsigned short* wp = wcat + (K_ << 6);                           \
        _Pragma("unroll")                                                      \
        for (int j = 0; j < 2; ++j)                                            \
            gload16(wp + b_off[j], B_ + adstB + (j << 10));                    \
    } while (0)

#define COMPUTE1(BUF) do {                                                     \
        const char* A_ = (BUF); const char* B_ = (BUF) + 32768;                \
        _Pragma("unroll")                                                      \
        for (int ks = 0; ks < 2; ++ks) {                                       \
            bf16x8 af[2];                                                      \
            _Pragma("unroll")                                                  \
            for (int mi = 0; mi < 2; ++mi) {                                   \
                int r = wm + mi * 16 + li;                                     \
                int c0 = ks * 8 + lh * 2;                                      \
                f32x4 a0 = *(const f32x4*)(A_ + r * 256 +                      \
                                           ((c0 ^ (r & 15)) << 4));            \
                f32x4 a1 = *(const f32x4*)(A_ + r * 256 +                      \
                                           (((c0 + 1) ^ (r & 15)) << 4));      \
                bf16x4 h0 = __builtin_convertvector(a0, bf16x4);               \
                bf16x4 h1 = __builtin_convertvector(a1, bf16x4);               \
                af[mi] = __builtin_shufflevector(h0, h1, 0,1,2,3,4,5,6,7);     \
            }                                                                  \
            int c = ks * 4 + lh;                                               \
            _Pragma("unroll")                                                  \
            for (int nj = 0; nj < 4; ++nj) {                                   \
                int rb = wn + nj * 16 + li;                                    \
                bf16x8 bv = *(const bf16x8*)(B_ + rb * 128 +                   \
                                             ((c ^ (rb & 7)) << 4));           \
                acc[0][nj] = __builtin_amdgcn_mfma_f32_16x16x32_bf16(          \
                    af[0], bv, acc[0][nj], 0, 0, 0);                           \
                acc[1][nj] = __builtin_amdgcn_mfma_f32_16x16x32_bf16(          \
                    af[1], bv, acc[1][nj], 0, 0, 0);                           \
            }                                                                  \
        }                                                                      \
    } while (0)

        char* p0 = lds; char* p1 = lds + 49152; char* p2 = lds + 98304;
        STAGE1(0, p0);
        STAGE1(1, p1);
        #pragma unroll 1
        for (int t = 0; t < 17; ++t) {
            WAITB(6);                          // tile t retired; t+1 in flight
            if (t + 2 < 18) STAGE1(t + 2, p2);
            COMPUTE1(p0);
            char* tmp = p0; p0 = p1; p1 = p2; p2 = tmp;
        }
        WAITB(0);
        COMPUTE1(p0);                          // tile 17
#undef STAGE1
#undef COMPUTE1

        // epilogue: bias+tanh, bf16 chunk-swizzled store (phase-2-ready)
        #pragma unroll
        for (int nj = 0; nj < 4; ++nj) {
            int gn = n0 + wn + nj * 16 + li;
            float bb = bsum[gn];
            #pragma unroll
            for (int mi = 0; mi < 2; ++mi) {
                #pragma unroll
                for (int r = 0; r < 4; ++r) {
                    int gm = m0 + wm + mi * 16 + (lh << 2) + r;
                    float v = tanh_fast(acc[mi][nj][r] + bb);
                    int ad = gm * 512 + (gn & ~63) +
                             ((((gn >> 3) & 7) ^ (gm & 7)) << 3) + (gn & 7);
                    ionew[ad] = f2bf(v);
                }
            }
        }
    }

    grid_barrier(bar);

    // ========================= phase 2: gemm2 ==============================
    // y = tanh(ionew @ w2s^T + b4). M=8192 N=128 K=512. BM=32 BN=128,
    // 8 waves (2m x 4n, wave 16x32). Double-K staging (128 cols/stage):
    // A 8KB + B 32KB per buffer, 2 buffers @ lds+{0,40960}. 5 loads/wave,
    // WAITB(5). XCD-affine: rows read on their phase-1 writer XCD.
    {
        const int m0 = ((((b & 7) << 3) | ((b >> 3) & 7)) << 7) + ((b >> 6) << 5);
        const int wm = (wid >> 2) << 4;       // 0/16
        const int wn = (wid & 3) << 5;        // 0/32/64/96

        // A: wave w stages rows [8*(w>>1), +8) of k-half (w&1): 1 issue.
        const int arow = (wid >> 1) << 3;
        const int ahalf = wid & 1;
        const size_t a_src = (size_t)(m0 + arow + (lane >> 3)) * 512 +
                             (ahalf << 6) + ((lane & 7) << 3);
        const int a_dst = (ahalf << 12) + ((wid >> 1) << 10);
        // B: wave w stages rows [16w, 16w+16) x both halves: 4 issues.
        size_t b_src[4]; int b_dst[4];
        #pragma unroll
        for (int j = 0; j < 4; ++j) {
            int h = j >> 1, rp = j & 1;
            b_src[j] = (size_t)((wid << 4) + (rp << 3) + (lane >> 3)) * 512 +
                       (h << 6) + ((lane & 7) << 3);
            b_dst[j] = (h << 14) + (wid << 11) + (rp << 10);
        }

        f32x4 zz = {0.f, 0.f, 0.f, 0.f};
        f32x4 acc2[2];
        acc2[0] = zz; acc2[1] = zz;

#define P2STAGE(T, BASE) do {                                                  \
        char* A_ = lds + (BASE); char* B_ = lds + (BASE) + 8192;               \
        gload16(ionew + a_src + (size_t)(T) * 128, A_ + a_dst);                \
        _Pragma("unroll")                                                      \
        for (int j = 0; j < 4; ++j)                                            \
            gload16(w2s + b_src[j] + (size_t)(T) * 128, B_ + b_dst[j]);        \
    } while (0)

#define P2COMPUTE(BASE) do {                                                   \
        const char* A_ = lds + (BASE); const char* B_ = lds + (BASE) + 8192;   \
        _Pragma("unroll")                                                      \
        for (int k4 = 0; k4 < 4; ++k4) {                                       \
            int h = k4 >> 1;                                                   \
            int c = (k4 & 1) * 4 + lh;                                         \
            int r = wm + li;                                                   \
            bf16x8 af = *(const bf16x8*)(A_ + h * 4096 + r * 128 +             \
                                         ((c ^ (r & 7)) << 4));                \
            _Pragma("unroll")                                                  \
            for (int nj = 0; nj < 2; ++nj) {                                   \
                int rb = wn + nj * 16 + li;                                    \
                bf16x8 bv = *(const bf16x8*)(B_ + h * 16384 + rb * 128 +       \
                                             ((c ^ (rb & 7)) << 4));           \
                acc2[nj] = __builtin_amdgcn_mfma_f32_16x16x32_bf16(            \
                    af, bv, acc2[nj], 0, 0, 0);                                \
            }                                                                  \
        }                                                                      \
    } while (0)

        P2STAGE(0, 0);
        P2STAGE(1, 40960);
        #pragma unroll 1
        for (int T = 0; T < 4; ++T) {
            if (T < 3) { WAITB(5); } else { WAITB(0); }
            int cb = (T & 1) ? 40960 : 0;
            P2COMPUTE(cb);
            if (T + 2 < 4) {
                BARL();
                P2STAGE(T + 2, cb);
            }
        }
#undef P2STAGE
#undef P2COMPUTE

        int n = wn + ((lane >> 4) << 0);  // placeholder avoided; compute below
        (void)n;
        #pragma unroll
        for (int nj = 0; nj < 2; ++nj) {
            int col = wn + nj * 16 + li;
            float bb = b4[col];
            #pragma unroll
            for (int r = 0; r < 4; ++r) {
                int row = m0 + wm + (lh << 2) + r;
                out[(size_t)row * 128 + col] = tanh_fast(acc2[nj][r] + bb);
            }
        }
    }
}

// ---------------------------------------------------------------------------
extern "C" void kernel_launch(void* const* d_in, const int* in_sizes, int n_in,
                              void* d_out, int out_size, void* d_ws, size_t ws_size,
                              hipStream_t stream)
{
    const float* x      = (const float*)d_in[0];
    const float* io     = (const float*)d_in[1];
    const float* cf     = (const float*)d_in[2];
    // d_in[3] cs_state: dead (does not feed y)
    const float* Wi2io  = (const float*)d_in[4];
    const float* bi2io  = (const float*)d_in[5];
    const float* Wio2o  = (const float*)d_in[6];
    const float* bio2o  = (const float*)d_in[7];
    const float* Wio2io = (const float*)d_in[8];
    const float* bio2io = (const float*)d_in[9];
    const float* Wcf2io = (const float*)d_in[12];
    const float* bcf2io = (const float*)d_in[13];
    float* out = (float*)d_out;

    // ws: wcat 1,179,648 | w2s 131,072 | bsum 2,048 | ionew 8,388,608 | bar 8
    char* ws = (char*)d_ws;
    unsigned short* wcat  = (unsigned short*)ws;
    unsigned short* w2s   = (unsigned short*)(ws + 1179648);
    float*          bsum  = (float*)(ws + 1310720);
    unsigned short* ionew = (unsigned short*)(ws + 1312768);
    unsigned*       bar   = (unsigned*)(ws + 9701376);

    hipMemsetAsync(bar, 0, 8, stream);   // reset grid-barrier state (capturable)
    hipLaunchKernelGGL(k_all, dim3(256), dim3(512), 0, stream,
                       x, io, cf, Wi2io, Wio2io, Wcf2io, Wio2o,
                       bi2io, bio2io, bcf2io, bio2o,
                       wcat, w2s, bsum, ionew, bar, out);
}